// Round 5
// baseline (224.596 us; speedup 1.0000x reference)
//
#include <hip/hip_runtime.h>
#include <hip/hip_bf16.h>

#define BATCH 256
#define NQ 1000
#define NC 80
#define QC 80000      // NQ*NC
#define KTOP 300
#define NBINS 4096
#define CAP 1024
#define T0 2.55f      // static pre-threshold: ~431 exp. candidates/batch, >=300 at -6.3 sigma

#define SLICES 8
#define K1_NT 256
#define F4_PER_SLICE (QC / 4 / SLICES)   // 2500 float4s per slice
#define K2_NT 1024

// order-preserving map f32 -> u32 (monotone: larger float -> larger uint)
__device__ __forceinline__ unsigned mono_key(float x) {
    unsigned u = __float_as_uint(x);
    return (u & 0x80000000u) ? ~u : (u | 0x80000000u);
}
__device__ __forceinline__ float inv_key(unsigned k) {
    unsigned u = (k & 0x80000000u) ? (k & 0x7FFFFFFFu) : ~k;
    return __uint_as_float(u);
}

// Bit-exact replica of XLA's logistic: 0.5 + 0.5*tanh(0.5*x)  (verified absmax 0.0)
__device__ __forceinline__ float ref_sigmoid(float x) {
    float in = __fmul_rn(0.5f, x);
    float xc = fminf(fmaxf(in, -7.90531110763549805f), 7.90531110763549805f);
    float x2 = __fmul_rn(xc, xc);
    float p = fmaf(x2, -2.76076847742355e-16f, 2.00018790482477e-13f);
    p = fmaf(x2, p, -8.60467152213735e-11f);
    p = fmaf(x2, p,  5.12229709037114e-08f);
    p = fmaf(x2, p,  1.48572235717979e-05f);
    p = fmaf(x2, p,  6.37261928875436e-04f);
    p = fmaf(x2, p,  4.89352455891786e-03f);
    float num = __fmul_rn(xc, p);
    float den = fmaf(x2, 1.19825839466702e-06f, 1.18534705686654e-04f);
    den = fmaf(x2, den, 2.26843463243900e-03f);
    den = fmaf(x2, den, 4.89352518554385e-03f);
    float t = num / den;
    t = (fabsf(in) < 0.0004f) ? in : t;
    return __fadd_rn(0.5f, __fmul_rn(0.5f, t));
}

// ---- kernel 1: pure streaming threshold scan (no LDS, no barriers) ----
__global__ __launch_bounds__(K1_NT)
void scan_kernel(const float* __restrict__ logits,
                 unsigned* __restrict__ counters,
                 unsigned long long* __restrict__ ckeys) {
    const int blk = blockIdx.x;
    const int b = blk / SLICES;
    const int s = blk % SLICES;
    const float4* lg4 = (const float4*)(logits + (size_t)b * QC) + s * F4_PER_SLICE;
    const int base4 = s * F4_PER_SLICE;

    for (int i = threadIdx.x; i < F4_PER_SLICE; i += K1_NT) {
        float4 v = lg4[i];
        float xs[4] = {v.x, v.y, v.z, v.w};
        #pragma unroll
        for (int j = 0; j < 4; ++j) {
            if (xs[j] >= T0) {
                unsigned pos = atomicAdd(&counters[b], 1u);
                if (pos < CAP) {
                    unsigned sk = mono_key(ref_sigmoid(xs[j]));
                    unsigned idx = (unsigned)((base4 + i) * 4 + j);
                    ckeys[(size_t)b * CAP + pos] =
                        ((unsigned long long)sk << 32) | (unsigned)(~idx);
                }
            }
        }
    }
}

// ---- kernel 2: rank selection + output (fallback: exact histogram path) ----
__global__ __launch_bounds__(K2_NT)
void select_kernel(const float* __restrict__ logits,
                   const float* __restrict__ boxes,
                   const float* __restrict__ sizes,
                   const unsigned* __restrict__ counters,
                   const unsigned long long* __restrict__ ckeys,
                   float* __restrict__ out) {
    __shared__ unsigned long long cand[CAP];
    __shared__ unsigned hist[NBINS];     // fallback only
    __shared__ unsigned scan[K2_NT];     // fallback only
    __shared__ unsigned s_tbin, s_count;

    const int b = blockIdx.x;
    const int tid = threadIdx.x;
    unsigned cnt = counters[b];

    if (cnt >= KTOP && cnt <= CAP) {
        // common path: candidates already in global scratch
        if (tid < (int)cnt) cand[tid] = ckeys[(size_t)b * CAP + tid];
        __syncthreads();
    } else {
        // exact fallback: full histogram threshold + recollect
        const float4* lg4 = (const float4*)(logits + (size_t)b * QC);
        for (int i = tid; i < NBINS; i += K2_NT) hist[i] = 0;
        if (tid == 0) s_count = 0;
        __syncthreads();
        for (int i = tid; i < QC / 4; i += K2_NT) {
            float4 v = lg4[i];
            atomicAdd(&hist[mono_key(v.x) >> 20], 1u);
            atomicAdd(&hist[mono_key(v.y) >> 20], 1u);
            atomicAdd(&hist[mono_key(v.z) >> 20], 1u);
            atomicAdd(&hist[mono_key(v.w) >> 20], 1u);
        }
        __syncthreads();
        unsigned h0 = hist[tid * 4 + 0], h1 = hist[tid * 4 + 1];
        unsigned h2 = hist[tid * 4 + 2], h3 = hist[tid * 4 + 3];
        scan[tid] = h0 + h1 + h2 + h3;
        __syncthreads();
        for (int off = 1; off < K2_NT; off <<= 1) {
            unsigned v = (tid + off < K2_NT) ? scan[tid + off] : 0u;
            __syncthreads();
            scan[tid] += v;
            __syncthreads();
        }
        unsigned run = (tid + 1 < K2_NT) ? scan[tid + 1] : 0u;
        unsigned hs[4] = {h3, h2, h1, h0};
        #pragma unroll
        for (int j = 0; j < 4; ++j) {
            unsigned bin = (unsigned)(tid * 4 + (3 - j));
            if (run < KTOP && KTOP <= run + hs[j]) s_tbin = bin;
            run += hs[j];
        }
        __syncthreads();
        unsigned thresh = s_tbin << 20;
        thresh = (thresh >= 4096u) ? thresh - 4096u : 0u;
        for (int i = tid; i < QC / 4; i += K2_NT) {
            float4 v = lg4[i];
            float xs[4] = {v.x, v.y, v.z, v.w};
            #pragma unroll
            for (int j = 0; j < 4; ++j) {
                if (mono_key(xs[j]) >= thresh) {
                    unsigned pos = atomicAdd(&s_count, 1u);
                    if (pos < CAP) {
                        unsigned sk = mono_key(ref_sigmoid(xs[j]));
                        unsigned idx = (unsigned)(i * 4 + j);
                        cand[pos] = ((unsigned long long)sk << 32) | (unsigned)(~idx);
                    }
                }
            }
        }
        __syncthreads();
        cnt = s_count; if (cnt > CAP) cnt = CAP;
    }

    // rank selection: rank = #keys greater; unique keys -> unique ranks
    if (tid < (int)cnt) {
        unsigned long long my = cand[tid];
        unsigned rank = 0;
        for (unsigned j = 0; j < cnt; ++j) rank += (cand[j] > my) ? 1u : 0u;
        if (rank < KTOP) {
            unsigned sk = (unsigned)(my >> 32);
            unsigned idx = ~((unsigned)my);
            float score = inv_key(sk);
            unsigned label = idx % NC;
            unsigned qi = idx / NC;
            float4 bx = ((const float4*)boxes)[(size_t)b * NQ + qi];
            float W = sizes[b * 2 + 0];
            float H = sizes[b * 2 + 1];
            float x0 = (bx.x - 0.5f * bx.z) * W;
            float y0 = (bx.y - 0.5f * bx.w) * H;
            float x1 = (bx.x + 0.5f * bx.z) * W;
            float y1 = (bx.y + 0.5f * bx.w) * H;
            int o = b * KTOP + (int)rank;
            out[o] = (float)label;
            float* ob = out + BATCH * KTOP;
            ob[(size_t)o * 4 + 0] = x0;
            ob[(size_t)o * 4 + 1] = y0;
            ob[(size_t)o * 4 + 2] = x1;
            ob[(size_t)o * 4 + 3] = y1;
            float* os = out + BATCH * KTOP * 5;
            os[o] = score;
        }
    }
}

extern "C" void kernel_launch(void* const* d_in, const int* in_sizes, int n_in,
                              void* d_out, int out_size, void* d_ws, size_t ws_size,
                              hipStream_t stream) {
    const float* logits = (const float*)d_in[0];
    const float* boxes  = (const float*)d_in[1];
    const float* sizes  = (const float*)d_in[2];
    float* out = (float*)d_out;

    // d_ws layout: [0, 1024) per-batch counters (256 x u32), then candidate keys
    unsigned* counters = (unsigned*)d_ws;
    unsigned long long* ckeys = (unsigned long long*)((char*)d_ws + 1024);

    hipMemsetAsync(counters, 0, BATCH * sizeof(unsigned), stream);
    scan_kernel<<<BATCH * SLICES, K1_NT, 0, stream>>>(logits, counters, ckeys);
    select_kernel<<<BATCH, K2_NT, 0, stream>>>(logits, boxes, sizes, counters, ckeys, out);
}

// Round 7
// 131.686 us; speedup vs baseline: 1.7055x; 1.7055x over previous
//
#include <hip/hip_runtime.h>
#include <hip/hip_bf16.h>

#define BATCH 256
#define NQ 1000
#define NC 80
#define QC 80000      // NQ*NC
#define KTOP 300
#define NBINS 4096
#define CAP 1024
#define T0 2.55f      // static pre-threshold: ~431 exp. candidates/batch, >=300 at -6.3 sigma

#define SLICES 8
#define SLOT 128      // per-slice candidate region (lambda~54, +10 sigma)
#define K1_NT 256
#define F4_PER_SLICE (QC / 4 / SLICES)   // 2500 float4s per slice
#define K2_NT 1024

// order-preserving map f32 -> u32 (monotone: larger float -> larger uint)
__device__ __forceinline__ unsigned mono_key(float x) {
    unsigned u = __float_as_uint(x);
    return (u & 0x80000000u) ? ~u : (u | 0x80000000u);
}
__device__ __forceinline__ float inv_key(unsigned k) {
    unsigned u = (k & 0x80000000u) ? (k & 0x7FFFFFFFu) : ~k;
    return __uint_as_float(u);
}

// Bit-exact replica of XLA's logistic: 0.5 + 0.5*tanh(0.5*x)  (verified absmax 0.0)
__device__ __forceinline__ float ref_sigmoid(float x) {
    float in = __fmul_rn(0.5f, x);
    float xc = fminf(fmaxf(in, -7.90531110763549805f), 7.90531110763549805f);
    float x2 = __fmul_rn(xc, xc);
    float p = fmaf(x2, -2.76076847742355e-16f, 2.00018790482477e-13f);
    p = fmaf(x2, p, -8.60467152213735e-11f);
    p = fmaf(x2, p,  5.12229709037114e-08f);
    p = fmaf(x2, p,  1.48572235717979e-05f);
    p = fmaf(x2, p,  6.37261928875436e-04f);
    p = fmaf(x2, p,  4.89352455891786e-03f);
    float num = __fmul_rn(xc, p);
    float den = fmaf(x2, 1.19825839466702e-06f, 1.18534705686654e-04f);
    den = fmaf(x2, den, 2.26843463243900e-03f);
    den = fmaf(x2, den, 4.89352518554385e-03f);
    float t = num / den;
    t = (fabsf(in) < 0.0004f) ? in : t;
    return __fadd_rn(0.5f, __fmul_rn(0.5f, t));
}

// ---- kernel 1: streaming threshold scan; block-local LDS counter, private
// ---- per-slice output region, ZERO global atomics ----
__global__ __launch_bounds__(K1_NT)
void scan_kernel(const float* __restrict__ logits,
                 unsigned* __restrict__ counters,
                 unsigned long long* __restrict__ ckeys) {
    __shared__ unsigned s_cnt;
    const int blk = blockIdx.x;
    const int b = blk / SLICES;
    const int s = blk % SLICES;
    const float4* lg4 = (const float4*)(logits + (size_t)b * QC) + s * F4_PER_SLICE;
    const int base4 = s * F4_PER_SLICE;
    unsigned long long* my_keys = ckeys + (size_t)b * CAP + (size_t)s * SLOT;

    if (threadIdx.x == 0) s_cnt = 0;
    __syncthreads();

    for (int i = threadIdx.x; i < F4_PER_SLICE; i += K1_NT) {
        float4 v = lg4[i];
        float xs[4] = {v.x, v.y, v.z, v.w};
        #pragma unroll
        for (int j = 0; j < 4; ++j) {
            if (xs[j] >= T0) {
                unsigned pos = atomicAdd(&s_cnt, 1u);   // LDS atomic, block-local
                if (pos < SLOT) {
                    unsigned sk = mono_key(ref_sigmoid(xs[j]));
                    unsigned idx = (unsigned)((base4 + i) * 4 + j);
                    my_keys[pos] = ((unsigned long long)sk << 32) | (unsigned)(~idx);
                }
            }
        }
    }
    __syncthreads();
    if (threadIdx.x == 0) counters[b * SLICES + s] = s_cnt;  // plain store
}

// ---- kernel 2: compact slices -> rank selection (fallback: exact histogram) ----
__global__ __launch_bounds__(K2_NT)
void select_kernel(const float* __restrict__ logits,
                   const float* __restrict__ boxes,
                   const float* __restrict__ sizes,
                   const unsigned* __restrict__ counters,
                   const unsigned long long* __restrict__ ckeys,
                   float* __restrict__ out) {
    __shared__ unsigned long long cand[CAP];
    __shared__ unsigned hist[NBINS];     // fallback only
    __shared__ unsigned scan[K2_NT];     // fallback only
    __shared__ unsigned s_tbin, s_count;

    const int b = blockIdx.x;
    const int tid = threadIdx.x;

    // read per-slice counts, prefix-sum in registers
    unsigned c[SLICES], pre[SLICES];
    unsigned total = 0;
    bool overflow = false;
    #pragma unroll
    for (int s = 0; s < SLICES; ++s) {
        c[s] = counters[b * SLICES + s];
        pre[s] = total;
        total += c[s];
        if (c[s] > SLOT) overflow = true;
    }
    unsigned cnt = total;

    if (!overflow && total >= KTOP && total <= CAP) {
        // common path: compact the 8 private regions into cand[]
        #pragma unroll
        for (int s = 0; s < SLICES; ++s) {
            if (tid < (int)c[s])
                cand[pre[s] + tid] = ckeys[(size_t)b * CAP + (size_t)s * SLOT + tid];
        }
        __syncthreads();
    } else {
        // exact fallback: full histogram threshold + recollect
        const float4* lg4 = (const float4*)(logits + (size_t)b * QC);
        for (int i = tid; i < NBINS; i += K2_NT) hist[i] = 0;
        if (tid == 0) s_count = 0;
        __syncthreads();
        for (int i = tid; i < QC / 4; i += K2_NT) {
            float4 v = lg4[i];
            atomicAdd(&hist[mono_key(v.x) >> 20], 1u);
            atomicAdd(&hist[mono_key(v.y) >> 20], 1u);
            atomicAdd(&hist[mono_key(v.z) >> 20], 1u);
            atomicAdd(&hist[mono_key(v.w) >> 20], 1u);
        }
        __syncthreads();
        unsigned h0 = hist[tid * 4 + 0], h1 = hist[tid * 4 + 1];
        unsigned h2 = hist[tid * 4 + 2], h3 = hist[tid * 4 + 3];
        scan[tid] = h0 + h1 + h2 + h3;
        __syncthreads();
        for (int off = 1; off < K2_NT; off <<= 1) {
            unsigned v = (tid + off < K2_NT) ? scan[tid + off] : 0u;
            __syncthreads();
            scan[tid] += v;
            __syncthreads();
        }
        unsigned run = (tid + 1 < K2_NT) ? scan[tid + 1] : 0u;
        unsigned hs[4] = {h3, h2, h1, h0};
        #pragma unroll
        for (int j = 0; j < 4; ++j) {
            unsigned bin = (unsigned)(tid * 4 + (3 - j));
            if (run < KTOP && KTOP <= run + hs[j]) s_tbin = bin;
            run += hs[j];
        }
        __syncthreads();
        unsigned thresh = s_tbin << 20;
        thresh = (thresh >= 4096u) ? thresh - 4096u : 0u;
        for (int i = tid; i < QC / 4; i += K2_NT) {
            float4 v = lg4[i];
            float xs[4] = {v.x, v.y, v.z, v.w};
            #pragma unroll
            for (int j = 0; j < 4; ++j) {
                if (mono_key(xs[j]) >= thresh) {
                    unsigned pos = atomicAdd(&s_count, 1u);
                    if (pos < CAP) {
                        unsigned sk = mono_key(ref_sigmoid(xs[j]));
                        unsigned idx = (unsigned)(i * 4 + j);
                        cand[pos] = ((unsigned long long)sk << 32) | (unsigned)(~idx);
                    }
                }
            }
        }
        __syncthreads();
        cnt = s_count; if (cnt > CAP) cnt = CAP;
    }

    // rank selection: rank = #keys greater; unique keys -> unique ranks
    if (tid < (int)cnt) {
        unsigned long long my = cand[tid];
        unsigned rank = 0;
        for (unsigned j = 0; j < cnt; ++j) rank += (cand[j] > my) ? 1u : 0u;
        if (rank < KTOP) {
            unsigned sk = (unsigned)(my >> 32);
            unsigned idx = ~((unsigned)my);
            float score = inv_key(sk);
            unsigned label = idx % NC;
            unsigned qi = idx / NC;
            float4 bx = ((const float4*)boxes)[(size_t)b * NQ + qi];
            float W = sizes[b * 2 + 0];
            float H = sizes[b * 2 + 1];
            float x0 = (bx.x - 0.5f * bx.z) * W;
            float y0 = (bx.y - 0.5f * bx.w) * H;
            float x1 = (bx.x + 0.5f * bx.z) * W;
            float y1 = (bx.y + 0.5f * bx.w) * H;
            int o = b * KTOP + (int)rank;
            out[o] = (float)label;
            float* ob = out + BATCH * KTOP;
            ob[(size_t)o * 4 + 0] = x0;
            ob[(size_t)o * 4 + 1] = y0;
            ob[(size_t)o * 4 + 2] = x1;
            ob[(size_t)o * 4 + 3] = y1;
            float* os = out + BATCH * KTOP * 5;
            os[o] = score;
        }
    }
}

extern "C" void kernel_launch(void* const* d_in, const int* in_sizes, int n_in,
                              void* d_out, int out_size, void* d_ws, size_t ws_size,
                              hipStream_t stream) {
    const float* logits = (const float*)d_in[0];
    const float* boxes  = (const float*)d_in[1];
    const float* sizes  = (const float*)d_in[2];
    float* out = (float*)d_out;

    // d_ws layout: [0, 8192) per-(batch,slice) counts (2048 x u32), then keys
    unsigned* counters = (unsigned*)d_ws;
    unsigned long long* ckeys = (unsigned long long*)((char*)d_ws + 8192);

    scan_kernel<<<BATCH * SLICES, K1_NT, 0, stream>>>(logits, counters, ckeys);
    select_kernel<<<BATCH, K2_NT, 0, stream>>>(logits, boxes, sizes, counters, ckeys, out);
}